// Round 14
// baseline (405.882 us; speedup 1.0000x reference)
//
#include <hip/hip_runtime.h>

#define B_   8
#define C_   256
#define D_   32
#define N_   4096
#define FMX  64.0f
// P swizzle on the 16B-unit index (write-side pprt and read-side q4 both reach
// the bank bits; bijective). Measured: conflicts 4.7M -> 524K.
#define PSWZ2(u) ((u) ^ (((u) >> 3) & 7) ^ ((((u) >> 6) & 3) << 1))
#define VBUF 32768   // one V tile: 8 p-blocks * 256 ch * 16B, linear

typedef __attribute__((ext_vector_type(8))) short bf8_t;   // 8 bf16 (4 VGPRs)
typedef __attribute__((ext_vector_type(4))) float f4_t;    // MFMA C/D frag

__device__ __forceinline__ unsigned short f2bf(float f) {   // fp32 -> bf16 RNE
    unsigned int u = __builtin_bit_cast(unsigned int, f);
    u += 0x7FFFu + ((u >> 16) & 1u);
    return (unsigned short)(u >> 16);
}
__device__ __forceinline__ float bf2f(unsigned short h) {
    unsigned int u = ((unsigned int)h) << 16;
    return __builtin_bit_cast(float, u);
}
__device__ __forceinline__ uint4 pack8(const unsigned short* h) {
    uint4 u;
    u.x = h[0] | ((unsigned)h[1] << 16); u.y = h[2] | ((unsigned)h[3] << 16);
    u.z = h[4] | ((unsigned)h[5] << 16); u.w = h[6] | ((unsigned)h[7] << 16);
    return u;
}
__device__ __forceinline__ void gload_lds16(const void* g, void* l) {
    __builtin_amdgcn_global_load_lds(
        (const __attribute__((address_space(1))) unsigned int*)g,
        (__attribute__((address_space(3))) unsigned int*)l, 16, 0, 0);
}

struct IC0 { static constexpr int v = 0; };
struct IC1 { static constexpr int v = 1; };

// ---------------------------------------------------------------------------
// Kernel 0: weight prep — coalesced mapping (proven).
// ---------------------------------------------------------------------------
__global__ __launch_bounds__(256) void wprep_kernel(
    const float* __restrict__ qw, const float* __restrict__ vw,
    unsigned short* __restrict__ wqFh, unsigned short* __restrict__ wqFl,
    unsigned short* __restrict__ wvF)
{
    const int tid = blockIdx.x * 256 + threadIdx.x;   // 36*256 = 9216
    if (tid < 8192) {
        const int oc = tid >> 5, c0 = (tid & 31) * 8;
        const float* src = vw + oc * 256 + c0;
        unsigned short h[8];
        #pragma unroll
        for (int e = 0; e < 8; ++e) h[e] = f2bf(src[e]);
        const int k = (oc >> 4) * 512 + (c0 >> 5) * 64 + ((c0 >> 3) & 3) * 16 + (oc & 15);
        *(uint4*)(wvF + (size_t)k * 8) = pack8(h);
    } else if (tid < 9216) {
        const int t2 = tid - 8192;
        const int oc = t2 >> 5, c0 = (t2 & 31) * 8;
        const float* src = qw + oc * 256 + c0;
        unsigned short h[8], l[8];
        #pragma unroll
        for (int e = 0; e < 8; ++e) {
            h[e] = f2bf(src[e]);
            l[e] = f2bf(src[e] - bf2f(h[e]));
        }
        const int k = (oc >> 4) * 512 + (c0 >> 5) * 64 + ((c0 >> 3) & 3) * 16 + (oc & 15);
        *(uint4*)(wqFh + (size_t)k * 8) = pack8(h);
        *(uint4*)(wqFl + (size_t)k * 8) = pack8(l);
    }
}

// ---------------------------------------------------------------------------
// Kernel 1: MFMA projections (verbatim — passed five times).
// ---------------------------------------------------------------------------
__global__ __launch_bounds__(256, 4) void proj_kernel(
    const float* __restrict__ x, const unsigned short* __restrict__ wqFh,
    const unsigned short* __restrict__ wqFl, const unsigned short* __restrict__ wvF,
    const float* __restrict__ qb, const float* __restrict__ vb,
    unsigned short* __restrict__ qh, unsigned short* __restrict__ ql,
    unsigned short* __restrict__ vF)
{
    __shared__ __align__(16) unsigned short S[10240];

    const int t    = threadIdx.x;
    const int lane = t & 63;
    const int w    = t >> 6;
    const int q4   = lane >> 4;
    const int l15  = lane & 15;
    const int b    = blockIdx.x & 7;          // batch -> XCD pin
    const int tt   = blockIdx.x >> 3;         // 0..127, n-tile of 32
    const int i0   = tt * 32;

    {
        const int n  = lane & 31;
        const int hi = lane >> 5;
        const float* xb = x + (size_t)b * C_ * N_ + i0 + n;
        #pragma unroll
        for (int cc = 0; cc < 4; ++cc) {
            const int chi = w * 8 + cc * 2 + hi;
            float v[8];
            #pragma unroll
            for (int e = 0; e < 8; ++e) v[e] = xb[(size_t)(chi * 8 + e) * N_];
            unsigned short h[8];
            #pragma unroll
            for (int e = 0; e < 8; ++e) h[e] = f2bf(v[e]);
            *(uint4*)&S[(chi * 32 + (n ^ (chi & 3))) * 8] = pack8(h);
        }
    }
    __syncthreads();

    f4_t acc[4][2];
    #pragma unroll
    for (int mt = 0; mt < 4; ++mt)
        #pragma unroll
        for (int nt = 0; nt < 2; ++nt) acc[mt][nt] = (f4_t)0.0f;
    f4_t qacc[2];
    qacc[0] = (f4_t)0.0f; qacc[1] = (f4_t)0.0f;

    #pragma unroll
    for (int kk = 0; kk < 8; ++kk) {
        bf8_t Bh[2];
        #pragma unroll
        for (int nt = 0; nt < 2; ++nt)
            Bh[nt] = *(const bf8_t*)&S[((kk * 4 + q4) * 32 + nt * 16 + (l15 ^ q4)) * 8];
        bf8_t Av[4];
        #pragma unroll
        for (int mt = 0; mt < 4; ++mt)
            Av[mt] = *(const bf8_t*)&wvF[(size_t)(((w * 4 + mt) * 8 + kk) * 64 + lane) * 8];

        #pragma unroll
        for (int mt = 0; mt < 4; ++mt)
            #pragma unroll
            for (int nt = 0; nt < 2; ++nt)
                acc[mt][nt] = __builtin_amdgcn_mfma_f32_16x16x32_bf16(
                    Av[mt], Bh[nt], acc[mt][nt], 0, 0, 0);

        if (w < 2) {
            #pragma unroll
            for (int mq = 0; mq < 2; ++mq) {
                bf8_t Aqh = *(const bf8_t*)&wqFh[(size_t)((mq * 8 + kk) * 64 + lane) * 8];
                bf8_t Aql = *(const bf8_t*)&wqFl[(size_t)((mq * 8 + kk) * 64 + lane) * 8];
                qacc[mq] = __builtin_amdgcn_mfma_f32_16x16x32_bf16(Aqh, Bh[w], qacc[mq], 0, 0, 0);
                qacc[mq] = __builtin_amdgcn_mfma_f32_16x16x32_bf16(Aql, Bh[w], qacc[mq], 0, 0, 0);
            }
        }
    }

    if (w < 2) {
        const int iq = i0 + w * 16 + l15;
        #pragma unroll
        for (int mq = 0; mq < 2; ++mq) {
            float4 qb4 = *(const float4*)(qb + mq * 16 + q4 * 4);
            float qv[4] = {qacc[mq][0] + qb4.x, qacc[mq][1] + qb4.y,
                           qacc[mq][2] + qb4.z, qacc[mq][3] + qb4.w};
            unsigned short hr[4], lr[4];
            #pragma unroll
            for (int r = 0; r < 4; ++r) {
                hr[r] = f2bf(qv[r]);
                lr[r] = f2bf(qv[r] - bf2f(hr[r]));
            }
            uint2 uh, ul;
            uh.x = hr[0] | ((unsigned)hr[1] << 16); uh.y = hr[2] | ((unsigned)hr[3] << 16);
            ul.x = lr[0] | ((unsigned)lr[1] << 16); ul.y = lr[2] | ((unsigned)lr[3] << 16);
            size_t qoff = ((size_t)b * N_ + iq) * D_ + mq * 16 + q4 * 4;
            *(uint2*)(qh + qoff) = uh;
            *(uint2*)(ql + qoff) = ul;
        }
    }

    __syncthreads();
    #pragma unroll
    for (int mt = 0; mt < 4; ++mt) {
        float4 vb4 = *(const float4*)(vb + w * 64 + mt * 16 + q4 * 4);
        float bias[4] = {vb4.x, vb4.y, vb4.z, vb4.w};
        #pragma unroll
        for (int nt = 0; nt < 2; ++nt)
            #pragma unroll
            for (int r = 0; r < 4; ++r)
                S[(w * 64 + mt * 16 + q4 * 4 + r) * 40 + nt * 16 + l15] =
                    f2bf(acc[mt][nt][r] + bias[r]);
    }
    __syncthreads();
    #pragma unroll
    for (int k2 = 0; k2 < 4; ++k2) {
        int id  = k2 * 256 + t;
        int oc  = id >> 2, seg = id & 3;
        uint4 dat = *(const uint4*)&S[oc * 40 + seg * 8];
        size_t p  = (size_t)(tt & 1) * 4 + seg;
        size_t off = ((((size_t)b * 64 + (tt >> 1)) * 8 + p) * 256 + (oc ^ seg)) * 8;
        *(uint4*)(vF + off) = dat;
    }
}

// ---------------------------------------------------------------------------
// Kernel 2: MFMA flash attention.
// R14: 3 blocks/CU. Single V buffer (32KB) + P dbuf (16KB) = 48KB LDS.
// 2 barriers/jt (single V buf forces it) but the V-DMA is issued at body
// START and overlaps QK+exp+P-write before barrier1's vmcnt(0) drain; with
// 3 staggered blocks the residual latency is covered cross-block.
// Hazards: STAGE(jt) vs PV(jt-1) fenced by barrier2(jt-1); P[cur] write vs
// PV(jt-2) fenced twice; K(jt+1) issued with STAGE (drained barrier1).
// All proven components kept: PSWZ2, hoisted indices, f2bf, setprio,
// lacc w2/w3 split, epilogue.
// ---------------------------------------------------------------------------
__global__ __launch_bounds__(256, 3) void attn_kernel(
    const unsigned short* __restrict__ qh, const unsigned short* __restrict__ ql,
    const unsigned short* __restrict__ vF, const float* __restrict__ x,
    const float* __restrict__ gamma_p, float* __restrict__ out)
{
    __shared__ __align__(16) unsigned char SMEM[VBUF];       // single V buf / epilogue T
    __shared__ __align__(16) unsigned short Pb[2][4096];     // P dbuf (swizzled)
    float* T     = (float*)SMEM;
    float* rowl  = (float*)&Pb[0][0];                        // epilogue alias (64 f32)
    float* rowl2 = (float*)&Pb[0][128];                      // second partial (64 f32)

    const int t    = threadIdx.x;
    const int lane = t & 63;
    const int w    = t >> 6;
    const int q4   = lane >> 4;
    const int l15  = lane & 15;
    const int b    = blockIdx.x & 7;              // batch -> XCD pin
    const int i0   = (blockIdx.x >> 3) * 64;

    const unsigned short* qhb = qh + (size_t)b * N_ * D_;
    const unsigned short* qlb = ql + (size_t)b * N_ * D_;
    const unsigned short* vFb = vF + (size_t)b * 1048576;

    bf8_t Ah[4], Al[4];
    #pragma unroll
    for (int mt = 0; mt < 4; ++mt) {
        size_t off = (size_t)(i0 + mt * 16 + l15) * D_ + q4 * 8;
        Ah[mt] = *(const bf8_t*)(qhb + off);
        Al[mt] = *(const bf8_t*)(qlb + off);
    }

    // ---- hoisted loop-invariant LDS indices ----
    const int jl = w * 16 + l15;
    const int pprt = jl >> 3, jlo = jl & 7;
    int pwIdx[4][4];           // P write: u16 index within Pb[cur]
    #pragma unroll
    for (int mt = 0; mt < 4; ++mt)
        #pragma unroll
        for (int r = 0; r < 4; ++r) {
            int u = pprt * 64 + mt * 16 + q4 * 4 + r;
            pwIdx[mt][r] = PSWZ2(u) * 8 + jlo;
        }
    int rdIdx[2][4];           // P read (Af): u16 index
    #pragma unroll
    for (int kk = 0; kk < 2; ++kk)
        #pragma unroll
        for (int mt = 0; mt < 4; ++mt) {
            int u = (kk * 4 + q4) * 64 + mt * 16 + l15;
            rdIdx[kk][mt] = PSWZ2(u) * 8;
        }
    int bfOff[2][4];           // V read (Bf): byte offset within the single buffer
    #pragma unroll
    for (int kk = 0; kk < 2; ++kk)
        #pragma unroll
        for (int nt = 0; nt < 4; ++nt)
            bfOff[kk][nt] = (kk * 4 + q4) * 4096 +
                            ((w * 64 + nt * 16 + l15) ^ q4) * 16;

    f4_t acc[4][4];
    #pragma unroll
    for (int mt = 0; mt < 4; ++mt)
        #pragma unroll
        for (int nt = 0; nt < 4; ++nt) acc[mt][nt] = (f4_t)0.0f;

    f4_t lacc[4];
    #pragma unroll
    for (int mt = 0; mt < 4; ++mt) lacc[mt] = (f4_t)0.0f;
    bf8_t onesb;
    #pragma unroll
    for (int e = 0; e < 8; ++e) onesb[e] = (short)0x3F80;

    // rolling pointers
    const int koffBase = jl * D_ + q4 * 8;
    const unsigned short* khp = qhb + 2048 + koffBase;   // K tile jt+1
    const unsigned short* klp = qlb + 2048 + koffBase;
    const unsigned short* vjp = vFb;                     // V tile jt (staged in-body)

    // prologue: K(0) regs only (V tile 0 staged at body(0) start)
    bf8_t Bh = *(const bf8_t*)(qhb + koffBase);
    bf8_t Bl = *(const bf8_t*)(qlb + koffBase);

    auto body = [&](int jt, auto ic) {
        constexpr int cur = decltype(ic)::v;
        unsigned short* Pbc = &Pb[cur][0];

        // (1) STAGE V(jt) into the single buffer (prior reader PV(jt-1) was
        //     fenced by barrier2 of the previous body) + issue K(jt+1).
        #pragma unroll
        for (int i = 0; i < 8; ++i) {
            const int c = i * 4 + w;
            gload_lds16(vjp + c * 512 + lane * 8, &SMEM[c * 1024]);
        }
        vjp += 16384;
        bf8_t Bh_n = Bh, Bl_n = Bl;
        if (jt + 1 < N_ / 64) {
            Bh_n = *(const bf8_t*)khp;
            Bl_n = *(const bf8_t*)klp;
            khp += 2048; klp += 2048;
        }

        // (2) QK^T for tile jt — overlaps the in-flight DMA (regs only)
        f4_t s[4];
        #pragma unroll
        for (int mt = 0; mt < 4; ++mt) {
            f4_t a = (f4_t)0.0f;
            a = __builtin_amdgcn_mfma_f32_16x16x32_bf16(Ah[mt], Bh, a, 0, 0, 0);
            a = __builtin_amdgcn_mfma_f32_16x16x32_bf16(Ah[mt], Bl, a, 0, 0, 0);
            a = __builtin_amdgcn_mfma_f32_16x16x32_bf16(Al[mt], Bh, a, 0, 0, 0);
            s[mt] = a;
        }

        // (3) exp + bf16 convert + P write (still overlapping the DMA)
        #pragma unroll
        for (int mt = 0; mt < 4; ++mt)
            #pragma unroll
            for (int r = 0; r < 4; ++r)
                Pbc[pwIdx[mt][r]] = f2bf(__expf(s[mt][r] - FMX));

        __syncthreads();   // barrier1: vmcnt(0) drains DMA; P(jt) visible

        // (4) PV for tile jt
        __builtin_amdgcn_s_setprio(1);
        #pragma unroll
        for (int kk = 0; kk < 2; ++kk) {
            bf8_t Af[4], Bf[4];
            #pragma unroll
            for (int nt = 0; nt < 4; ++nt)
                Bf[nt] = *(const bf8_t*)&SMEM[bfOff[kk][nt]];
            #pragma unroll
            for (int mt = 0; mt < 4; ++mt)
                Af[mt] = *(const bf8_t*)&Pbc[rdIdx[kk][mt]];
            #pragma unroll
            for (int mt = 0; mt < 4; ++mt)
                #pragma unroll
                for (int nt = 0; nt < 4; ++nt)
                    acc[mt][nt] = __builtin_amdgcn_mfma_f32_16x16x32_bf16(
                        Af[mt], Bf[nt], acc[mt][nt], 0, 0, 0);
            if (w == 3 - kk) {   // kk=0 -> wave3, kk=1 -> wave2 (load balance)
                #pragma unroll
                for (int mt = 0; mt < 4; ++mt)
                    lacc[mt] = __builtin_amdgcn_mfma_f32_16x16x32_bf16(
                        Af[mt], onesb, lacc[mt], 0, 0, 0);
            }
        }
        __builtin_amdgcn_s_setprio(0);

        __syncthreads();   // barrier2: PV V-reads done -> next STAGE safe

        Bh = Bh_n; Bl = Bl_n;
    };

    for (int jtp = 0; jtp < N_ / 64; jtp += 2) {
        body(jtp,     IC0{});
        body(jtp + 1, IC1{});
    }

    // epilogue (rowl writes fenced by loop's final barrier2)
    if (w >= 2 && l15 == 0) {
        float* dst = (w == 3) ? rowl : rowl2;
        #pragma unroll
        for (int mt = 0; mt < 4; ++mt)
            #pragma unroll
            for (int r = 0; r < 4; ++r)
                dst[mt * 16 + q4 * 4 + r] = lacc[mt][r];
    }
    __syncthreads();

    const float g = gamma_p[0];
    for (int mt = 0; mt < 4; ++mt) {
        float4 rlA = *(float4*)(&rowl[mt * 16 + q4 * 4]);
        float4 rlB = *(float4*)(&rowl2[mt * 16 + q4 * 4]);
        float inv[4] = { g / (rlA.x + rlB.x), g / (rlA.y + rlB.y),
                         g / (rlA.z + rlB.z), g / (rlA.w + rlB.w) };
        #pragma unroll
        for (int nt = 0; nt < 4; ++nt)
            #pragma unroll
            for (int r = 0; r < 4; ++r)
                T[(w * 64 + nt * 16 + l15) * 17 + q4 * 4 + r] = acc[mt][nt][r] * inv[r];
        __syncthreads();
        #pragma unroll
        for (int pass = 0; pass < 4; ++pass) {
            int c  = pass * 64 + (t >> 2);
            int ii = (t & 3) * 4;
            float4 o;
            o.x = T[c * 17 + ii];     o.y = T[c * 17 + ii + 1];
            o.z = T[c * 17 + ii + 2]; o.w = T[c * 17 + ii + 3];
            size_t goff = ((size_t)b * C_ + c) * N_ + i0 + mt * 16 + ii;
            float4 xv = *(const float4*)(x + goff);
            o.x += xv.x; o.y += xv.y; o.z += xv.z; o.w += xv.w;
            *(float4*)(out + goff) = o;
        }
        __syncthreads();
    }
}

extern "C" void kernel_launch(void* const* d_in, const int* in_sizes, int n_in,
                              void* d_out, int out_size, void* d_ws, size_t ws_size,
                              hipStream_t stream)
{
    const float* x     = (const float*)d_in[0];
    const float* q_w   = (const float*)d_in[1];
    const float* q_b   = (const float*)d_in[2];
    const float* v_w   = (const float*)d_in[3];
    const float* v_b   = (const float*)d_in[4];
    const float* gamma = (const float*)d_in[5];
    float* out = (float*)d_out;

    unsigned short* ws16 = (unsigned short*)d_ws;
    unsigned short* qhp  = ws16;                   // 1M u16
    unsigned short* qlp  = ws16 + 1048576;         // 1M u16
    unsigned short* vFp  = ws16 + 2097152;         // 8M u16 (fragment-order V, c^p swizzled)
    unsigned short* wvF  = ws16 + 10485760;        // 64K u16
    unsigned short* wqFh = wvF + 65536;            // 8K u16
    unsigned short* wqFl = wqFh + 8192;            // 8K u16

    wprep_kernel<<<36, 256, 0, stream>>>(q_w, v_w, wqFh, wqFl, wvF);
    proj_kernel<<<B_ * (N_ / 32), 256, 0, stream>>>(x, wqFh, wqFl, wvF, q_b, v_b,
                                                    qhp, qlp, vFp);
    attn_kernel<<<B_ * (N_ / 64), 256, 0, stream>>>(qhp, qlp, vFp, x, gamma, out);
}

// Round 15
// 215.153 us; speedup vs baseline: 1.8865x; 1.8865x over previous
//
#include <hip/hip_runtime.h>

#define B_   8
#define C_   256
#define D_   32
#define N_   4096
#define FMX  64.0f
// P swizzle on the 16B-unit index (write-side pprt and read-side q4 both reach
// the bank bits; bijective). Measured: conflicts 4.7M -> 524K.
#define PSWZ2(u) ((u) ^ (((u) >> 3) & 7) ^ ((((u) >> 6) & 3) << 1))
#define VBUF 32768   // one V tile: 8 p-blocks * 256 ch * 16B, linear

typedef __attribute__((ext_vector_type(8))) short bf8_t;   // 8 bf16 (4 VGPRs)
typedef __attribute__((ext_vector_type(4))) float f4_t;    // MFMA C/D frag

__device__ __forceinline__ unsigned short f2bf(float f) {   // fp32 -> bf16 RNE
    unsigned int u = __builtin_bit_cast(unsigned int, f);
    u += 0x7FFFu + ((u >> 16) & 1u);
    return (unsigned short)(u >> 16);
}
__device__ __forceinline__ float bf2f(unsigned short h) {
    unsigned int u = ((unsigned int)h) << 16;
    return __builtin_bit_cast(float, u);
}
__device__ __forceinline__ uint4 pack8(const unsigned short* h) {
    uint4 u;
    u.x = h[0] | ((unsigned)h[1] << 16); u.y = h[2] | ((unsigned)h[3] << 16);
    u.z = h[4] | ((unsigned)h[5] << 16); u.w = h[6] | ((unsigned)h[7] << 16);
    return u;
}
__device__ __forceinline__ void gload_lds16(const void* g, void* l) {
    __builtin_amdgcn_global_load_lds(
        (const __attribute__((address_space(1))) unsigned int*)g,
        (__attribute__((address_space(3))) unsigned int*)l, 16, 0, 0);
}

struct IC0 { static constexpr int v = 0; };
struct IC1 { static constexpr int v = 1; };

// ---------------------------------------------------------------------------
// Kernel 0: weight prep — coalesced mapping (proven).
// ---------------------------------------------------------------------------
__global__ __launch_bounds__(256) void wprep_kernel(
    const float* __restrict__ qw, const float* __restrict__ vw,
    unsigned short* __restrict__ wqFh, unsigned short* __restrict__ wqFl,
    unsigned short* __restrict__ wvF)
{
    const int tid = blockIdx.x * 256 + threadIdx.x;   // 36*256 = 9216
    if (tid < 8192) {
        const int oc = tid >> 5, c0 = (tid & 31) * 8;
        const float* src = vw + oc * 256 + c0;
        unsigned short h[8];
        #pragma unroll
        for (int e = 0; e < 8; ++e) h[e] = f2bf(src[e]);
        const int k = (oc >> 4) * 512 + (c0 >> 5) * 64 + ((c0 >> 3) & 3) * 16 + (oc & 15);
        *(uint4*)(wvF + (size_t)k * 8) = pack8(h);
    } else if (tid < 9216) {
        const int t2 = tid - 8192;
        const int oc = t2 >> 5, c0 = (t2 & 31) * 8;
        const float* src = qw + oc * 256 + c0;
        unsigned short h[8], l[8];
        #pragma unroll
        for (int e = 0; e < 8; ++e) {
            h[e] = f2bf(src[e]);
            l[e] = f2bf(src[e] - bf2f(h[e]));
        }
        const int k = (oc >> 4) * 512 + (c0 >> 5) * 64 + ((c0 >> 3) & 3) * 16 + (oc & 15);
        *(uint4*)(wqFh + (size_t)k * 8) = pack8(h);
        *(uint4*)(wqFl + (size_t)k * 8) = pack8(l);
    }
}

// ---------------------------------------------------------------------------
// Kernel 1: MFMA projections (verbatim — passed five times).
// ---------------------------------------------------------------------------
__global__ __launch_bounds__(256, 4) void proj_kernel(
    const float* __restrict__ x, const unsigned short* __restrict__ wqFh,
    const unsigned short* __restrict__ wqFl, const unsigned short* __restrict__ wvF,
    const float* __restrict__ qb, const float* __restrict__ vb,
    unsigned short* __restrict__ qh, unsigned short* __restrict__ ql,
    unsigned short* __restrict__ vF)
{
    __shared__ __align__(16) unsigned short S[10240];

    const int t    = threadIdx.x;
    const int lane = t & 63;
    const int w    = t >> 6;
    const int q4   = lane >> 4;
    const int l15  = lane & 15;
    const int b    = blockIdx.x & 7;          // batch -> XCD pin
    const int tt   = blockIdx.x >> 3;         // 0..127, n-tile of 32
    const int i0   = tt * 32;

    {
        const int n  = lane & 31;
        const int hi = lane >> 5;
        const float* xb = x + (size_t)b * C_ * N_ + i0 + n;
        #pragma unroll
        for (int cc = 0; cc < 4; ++cc) {
            const int chi = w * 8 + cc * 2 + hi;
            float v[8];
            #pragma unroll
            for (int e = 0; e < 8; ++e) v[e] = xb[(size_t)(chi * 8 + e) * N_];
            unsigned short h[8];
            #pragma unroll
            for (int e = 0; e < 8; ++e) h[e] = f2bf(v[e]);
            *(uint4*)&S[(chi * 32 + (n ^ (chi & 3))) * 8] = pack8(h);
        }
    }
    __syncthreads();

    f4_t acc[4][2];
    #pragma unroll
    for (int mt = 0; mt < 4; ++mt)
        #pragma unroll
        for (int nt = 0; nt < 2; ++nt) acc[mt][nt] = (f4_t)0.0f;
    f4_t qacc[2];
    qacc[0] = (f4_t)0.0f; qacc[1] = (f4_t)0.0f;

    #pragma unroll
    for (int kk = 0; kk < 8; ++kk) {
        bf8_t Bh[2];
        #pragma unroll
        for (int nt = 0; nt < 2; ++nt)
            Bh[nt] = *(const bf8_t*)&S[((kk * 4 + q4) * 32 + nt * 16 + (l15 ^ q4)) * 8];
        bf8_t Av[4];
        #pragma unroll
        for (int mt = 0; mt < 4; ++mt)
            Av[mt] = *(const bf8_t*)&wvF[(size_t)(((w * 4 + mt) * 8 + kk) * 64 + lane) * 8];

        #pragma unroll
        for (int mt = 0; mt < 4; ++mt)
            #pragma unroll
            for (int nt = 0; nt < 2; ++nt)
                acc[mt][nt] = __builtin_amdgcn_mfma_f32_16x16x32_bf16(
                    Av[mt], Bh[nt], acc[mt][nt], 0, 0, 0);

        if (w < 2) {
            #pragma unroll
            for (int mq = 0; mq < 2; ++mq) {
                bf8_t Aqh = *(const bf8_t*)&wqFh[(size_t)((mq * 8 + kk) * 64 + lane) * 8];
                bf8_t Aql = *(const bf8_t*)&wqFl[(size_t)((mq * 8 + kk) * 64 + lane) * 8];
                qacc[mq] = __builtin_amdgcn_mfma_f32_16x16x32_bf16(Aqh, Bh[w], qacc[mq], 0, 0, 0);
                qacc[mq] = __builtin_amdgcn_mfma_f32_16x16x32_bf16(Aql, Bh[w], qacc[mq], 0, 0, 0);
            }
        }
    }

    if (w < 2) {
        const int iq = i0 + w * 16 + l15;
        #pragma unroll
        for (int mq = 0; mq < 2; ++mq) {
            float4 qb4 = *(const float4*)(qb + mq * 16 + q4 * 4);
            float qv[4] = {qacc[mq][0] + qb4.x, qacc[mq][1] + qb4.y,
                           qacc[mq][2] + qb4.z, qacc[mq][3] + qb4.w};
            unsigned short hr[4], lr[4];
            #pragma unroll
            for (int r = 0; r < 4; ++r) {
                hr[r] = f2bf(qv[r]);
                lr[r] = f2bf(qv[r] - bf2f(hr[r]));
            }
            uint2 uh, ul;
            uh.x = hr[0] | ((unsigned)hr[1] << 16); uh.y = hr[2] | ((unsigned)hr[3] << 16);
            ul.x = lr[0] | ((unsigned)lr[1] << 16); ul.y = lr[2] | ((unsigned)lr[3] << 16);
            size_t qoff = ((size_t)b * N_ + iq) * D_ + mq * 16 + q4 * 4;
            *(uint2*)(qh + qoff) = uh;
            *(uint2*)(ql + qoff) = ul;
        }
    }

    __syncthreads();
    #pragma unroll
    for (int mt = 0; mt < 4; ++mt) {
        float4 vb4 = *(const float4*)(vb + w * 64 + mt * 16 + q4 * 4);
        float bias[4] = {vb4.x, vb4.y, vb4.z, vb4.w};
        #pragma unroll
        for (int nt = 0; nt < 2; ++nt)
            #pragma unroll
            for (int r = 0; r < 4; ++r)
                S[(w * 64 + mt * 16 + q4 * 4 + r) * 40 + nt * 16 + l15] =
                    f2bf(acc[mt][nt][r] + bias[r]);
    }
    __syncthreads();
    #pragma unroll
    for (int k2 = 0; k2 < 4; ++k2) {
        int id  = k2 * 256 + t;
        int oc  = id >> 2, seg = id & 3;
        uint4 dat = *(const uint4*)&S[oc * 40 + seg * 8];
        size_t p  = (size_t)(tt & 1) * 4 + seg;
        size_t off = ((((size_t)b * 64 + (tt >> 1)) * 8 + p) * 256 + (oc ^ seg)) * 8;
        *(uint4*)(vF + off) = dat;
    }
}

// ---------------------------------------------------------------------------
// Kernel 2: MFMA flash attention — R13 VERBATIM (proven 216.6us total).
// R14's single-V-buffer "3 blocks/CU" was impossible: grid = 512 blocks on
// 256 CUs caps at 2 blocks/CU regardless of LDS; the exposed per-jt DMA
// drain cost 2.5x. Double-buffered V + P dbuf (80KB, 2 blocks/CU) restored.
// Proven components: DMA staging from fragment-ordered vF, PSWZ2 (conflicts
// 8.9M -> 524K), hoisted indices + unroll-2, setprio on PV, lacc w2/w3 split.
// ---------------------------------------------------------------------------
__global__ __launch_bounds__(256, 2) void attn_kernel(
    const unsigned short* __restrict__ qh, const unsigned short* __restrict__ ql,
    const unsigned short* __restrict__ vF, const float* __restrict__ x,
    const float* __restrict__ gamma_p, float* __restrict__ out)
{
    __shared__ __align__(16) unsigned char SMEM[2 * VBUF];   // V dbuf / epilogue T
    __shared__ __align__(16) unsigned short Pb[2][4096];     // P dbuf (swizzled)
    float* T     = (float*)SMEM;
    float* rowl  = (float*)&Pb[0][0];                        // epilogue alias (64 f32)
    float* rowl2 = (float*)&Pb[0][128];                      // second partial (64 f32)

    const int t    = threadIdx.x;
    const int lane = t & 63;
    const int w    = t >> 6;
    const int q4   = lane >> 4;
    const int l15  = lane & 15;
    const int b    = blockIdx.x & 7;              // batch -> XCD pin
    const int i0   = (blockIdx.x >> 3) * 64;

    const unsigned short* qhb = qh + (size_t)b * N_ * D_;
    const unsigned short* qlb = ql + (size_t)b * N_ * D_;
    const unsigned short* vFb = vF + (size_t)b * 1048576;

    bf8_t Ah[4], Al[4];
    #pragma unroll
    for (int mt = 0; mt < 4; ++mt) {
        size_t off = (size_t)(i0 + mt * 16 + l15) * D_ + q4 * 8;
        Ah[mt] = *(const bf8_t*)(qhb + off);
        Al[mt] = *(const bf8_t*)(qlb + off);
    }

    // ---- hoisted loop-invariant LDS indices ----
    const int jl = w * 16 + l15;
    const int pprt = jl >> 3, jlo = jl & 7;
    int pwIdx[4][4];           // P write: u16 index within Pb[cur]
    #pragma unroll
    for (int mt = 0; mt < 4; ++mt)
        #pragma unroll
        for (int r = 0; r < 4; ++r) {
            int u = pprt * 64 + mt * 16 + q4 * 4 + r;
            pwIdx[mt][r] = PSWZ2(u) * 8 + jlo;
        }
    int rdIdx[2][4];           // P read (Af): u16 index
    #pragma unroll
    for (int kk = 0; kk < 2; ++kk)
        #pragma unroll
        for (int mt = 0; mt < 4; ++mt) {
            int u = (kk * 4 + q4) * 64 + mt * 16 + l15;
            rdIdx[kk][mt] = PSWZ2(u) * 8;
        }
    int bfOff[2][4];           // V read (Bf): byte offset within buffer
    #pragma unroll
    for (int kk = 0; kk < 2; ++kk)
        #pragma unroll
        for (int nt = 0; nt < 4; ++nt)
            bfOff[kk][nt] = (kk * 4 + q4) * 4096 +
                            ((w * 64 + nt * 16 + l15) ^ q4) * 16;

    f4_t acc[4][4];
    #pragma unroll
    for (int mt = 0; mt < 4; ++mt)
        #pragma unroll
        for (int nt = 0; nt < 4; ++nt) acc[mt][nt] = (f4_t)0.0f;

    f4_t lacc[4];
    #pragma unroll
    for (int mt = 0; mt < 4; ++mt) lacc[mt] = (f4_t)0.0f;
    bf8_t onesb;
    #pragma unroll
    for (int e = 0; e < 8; ++e) onesb[e] = (short)0x3F80;

    // rolling pointers
    const int koffBase = jl * D_ + q4 * 8;
    const unsigned short* khp = qhb + 2048 + koffBase;   // K tile jt+1
    const unsigned short* klp = qlb + 2048 + koffBase;
    const unsigned short* vjp = vFb + 16384;             // V tile jt+1

    // prologue: K(0), stage V tile 0 into buffer 0
    bf8_t Bh = *(const bf8_t*)(qhb + koffBase);
    bf8_t Bl = *(const bf8_t*)(qlb + koffBase);
    {
        const unsigned short* vj = vFb;
        #pragma unroll
        for (int i = 0; i < 8; ++i) {
            const int c = i * 4 + w;
            gload_lds16(vj + c * 512 + lane * 8, &SMEM[c * 1024]);
        }
    }

    auto body = [&](int jt, auto ic) {
        constexpr int cur = decltype(ic)::v;
        unsigned short* Pbc = &Pb[cur][0];
        const unsigned char* Vsc = &SMEM[cur * VBUF];

        // QK^T for tile jt (K regs loaded last body / prologue)
        f4_t s[4];
        #pragma unroll
        for (int mt = 0; mt < 4; ++mt) {
            f4_t a = (f4_t)0.0f;
            a = __builtin_amdgcn_mfma_f32_16x16x32_bf16(Ah[mt], Bh, a, 0, 0, 0);
            a = __builtin_amdgcn_mfma_f32_16x16x32_bf16(Ah[mt], Bl, a, 0, 0, 0);
            a = __builtin_amdgcn_mfma_f32_16x16x32_bf16(Al[mt], Bh, a, 0, 0, 0);
            s[mt] = a;
        }

        // exp + scalar bf16 convert (f2bf — proven path)
        #pragma unroll
        for (int mt = 0; mt < 4; ++mt)
            #pragma unroll
            for (int r = 0; r < 4; ++r)
                Pbc[pwIdx[mt][r]] = f2bf(__expf(s[mt][r] - FMX));

        __syncthreads();   // P(jt) visible; STAGE(jt) DMA drained

        // K(jt+1) then STAGE(jt+1) into the other buffer
        if (jt + 1 < N_ / 64) {
            Bh = *(const bf8_t*)khp;
            Bl = *(const bf8_t*)klp;
            khp += 2048; klp += 2048;
            #pragma unroll
            for (int i = 0; i < 8; ++i) {
                const int c = i * 4 + w;
                gload_lds16(vjp + c * 512 + lane * 8,
                            &SMEM[(cur ^ 1) * VBUF + c * 1024]);
            }
            vjp += 16384;
        }

        // PV for tile jt (setprio around the MFMA-dense cluster — T5)
        __builtin_amdgcn_s_setprio(1);
        #pragma unroll
        for (int kk = 0; kk < 2; ++kk) {
            bf8_t Af[4], Bf[4];
            #pragma unroll
            for (int nt = 0; nt < 4; ++nt)
                Bf[nt] = *(const bf8_t*)&Vsc[bfOff[kk][nt]];
            #pragma unroll
            for (int mt = 0; mt < 4; ++mt)
                Af[mt] = *(const bf8_t*)&Pbc[rdIdx[kk][mt]];
            #pragma unroll
            for (int mt = 0; mt < 4; ++mt)
                #pragma unroll
                for (int nt = 0; nt < 4; ++nt)
                    acc[mt][nt] = __builtin_amdgcn_mfma_f32_16x16x32_bf16(
                        Af[mt], Bf[nt], acc[mt][nt], 0, 0, 0);
            if (w == 3 - kk) {   // kk=0 -> wave3, kk=1 -> wave2 (load balance)
                #pragma unroll
                for (int mt = 0; mt < 4; ++mt)
                    lacc[mt] = __builtin_amdgcn_mfma_f32_16x16x32_bf16(
                        Af[mt], onesb, lacc[mt], 0, 0, 0);
            }
        }
        __builtin_amdgcn_s_setprio(0);
    };

    for (int jtp = 0; jtp < N_ / 64; jtp += 2) {
        body(jtp,     IC0{});
        body(jtp + 1, IC1{});
    }

    __syncthreads();
    if (w >= 2 && l15 == 0) {
        float* dst = (w == 3) ? rowl : rowl2;
        #pragma unroll
        for (int mt = 0; mt < 4; ++mt)
            #pragma unroll
            for (int r = 0; r < 4; ++r)
                dst[mt * 16 + q4 * 4 + r] = lacc[mt][r];
    }
    __syncthreads();

    const float g = gamma_p[0];
    for (int mt = 0; mt < 4; ++mt) {
        float4 rlA = *(float4*)(&rowl[mt * 16 + q4 * 4]);
        float4 rlB = *(float4*)(&rowl2[mt * 16 + q4 * 4]);
        float inv[4] = { g / (rlA.x + rlB.x), g / (rlA.y + rlB.y),
                         g / (rlA.z + rlB.z), g / (rlA.w + rlB.w) };
        #pragma unroll
        for (int nt = 0; nt < 4; ++nt)
            #pragma unroll
            for (int r = 0; r < 4; ++r)
                T[(w * 64 + nt * 16 + l15) * 17 + q4 * 4 + r] = acc[mt][nt][r] * inv[r];
        __syncthreads();
        #pragma unroll
        for (int pass = 0; pass < 4; ++pass) {
            int c  = pass * 64 + (t >> 2);
            int ii = (t & 3) * 4;
            float4 o;
            o.x = T[c * 17 + ii];     o.y = T[c * 17 + ii + 1];
            o.z = T[c * 17 + ii + 2]; o.w = T[c * 17 + ii + 3];
            size_t goff = ((size_t)b * C_ + c) * N_ + i0 + mt * 16 + ii;
            float4 xv = *(const float4*)(x + goff);
            o.x += xv.x; o.y += xv.y; o.z += xv.z; o.w += xv.w;
            *(float4*)(out + goff) = o;
        }
        __syncthreads();
    }
}

extern "C" void kernel_launch(void* const* d_in, const int* in_sizes, int n_in,
                              void* d_out, int out_size, void* d_ws, size_t ws_size,
                              hipStream_t stream)
{
    const float* x     = (const float*)d_in[0];
    const float* q_w   = (const float*)d_in[1];
    const float* q_b   = (const float*)d_in[2];
    const float* v_w   = (const float*)d_in[3];
    const float* v_b   = (const float*)d_in[4];
    const float* gamma = (const float*)d_in[5];
    float* out = (float*)d_out;

    unsigned short* ws16 = (unsigned short*)d_ws;
    unsigned short* qhp  = ws16;                   // 1M u16
    unsigned short* qlp  = ws16 + 1048576;         // 1M u16
    unsigned short* vFp  = ws16 + 2097152;         // 8M u16 (fragment-order V, c^p swizzled)
    unsigned short* wvF  = ws16 + 10485760;        // 64K u16
    unsigned short* wqFh = wvF + 65536;            // 8K u16
    unsigned short* wqFl = wqFh + 8192;            // 8K u16

    wprep_kernel<<<36, 256, 0, stream>>>(q_w, v_w, wqFh, wqFl, wvF);
    proj_kernel<<<B_ * (N_ / 32), 256, 0, stream>>>(x, wqFh, wqFl, wvF, q_b, v_b,
                                                    qhp, qlp, vFp);
    attn_kernel<<<B_ * (N_ / 64), 256, 0, stream>>>(qhp, qlp, vFp, x, gamma, out);
}